// Round 2
// baseline (388.276 us; speedup 1.0000x reference)
//
#include <hip/hip_runtime.h>

// Net_3152505995417: tiny GNN forward (N=116, E=6670, HID=64, EDIM=5).
// R4: ONE single-workgroup kernel (1024 thr, 1 CU). All grid-wide dependency
// boundaries become __syncthreads(); all intermediates live in LDS (125 KB,
// precedent: verified 128-KiB plain-HIP template). Matmuls restructured to
// minimize LDS traffic:
//  - @W matmuls (X, Y1, Y2): 8 nodes/wave, weight row read once per k serves
//    8 outputs; small operand via wave-uniform scalar/broadcast reads.
//  - D@Y convs (116x116): lane=node, 32 h-accumulators/lane over 4 waves;
//    per-j cost = 1 per-lane d read + 8 uniform float4 Y reads.
// Math identical to the verified R0 kernels (same loop orders, same division
// in S, same shfl trees); only dv/pool reduction association differs (~1e-6).

#define NN   116
#define EE   6670
#define HID  64
#define EDIM 5
#define OUTD 4
#define ENC  122
#define EPSF 1e-10f
#define RS   68          // padded row stride for [116][64] LDS tiles (bank-spread, 16B-aligned)

__device__ __forceinline__ int eid_ij(int i, int j) {
    int a = i < j ? i : j;
    int b = i < j ? j : i;
    return a*NN - ((a*(a+1)) >> 1) + (b - a - 1);   // triu k=1 row-major
}

__global__ __launch_bounds__(1024) void fused1(
    const float* __restrict__ enc, const float* __restrict__ ea,
    const int* __restrict__ eidx,
    const float* __restrict__ W_enc, const float* __restrict__ b_enc,
    const float* __restrict__ W1, const float* __restrict__ b1,
    const float* __restrict__ p1, const float* __restrict__ We,
    const float* __restrict__ be, const float* __restrict__ pe,
    const float* __restrict__ W2, const float* __restrict__ b2,
    const float* __restrict__ p2, const float* __restrict__ Wl,
    const float* __restrict__ bl,
    float* __restrict__ G, float* __restrict__ out)
{
    __shared__ __align__(16) float sX [NN*RS];   // X rows (A), x2 rows (B)
    __shared__ __align__(16) float sY1[NN*RS];
    __shared__ __align__(16) float sY2[NN*RS];
    __shared__ __align__(16) float sD [EE];      // d1 then d2
    __shared__ float sDv[128];
    __shared__ float sDvP[256];
    __shared__ float sS[NN*EDIM];
    __shared__ float sP[HID];

    const int tid  = threadIdx.x;
    const int wid  = tid >> 6;
    const int lane = tid & 63;

    // ======== Phase A1: X = enc@W_enc + b_enc  (8 nodes per wave, 15 tasks) ========
    if (wid < 15) {
        const int i0 = __builtin_amdgcn_readfirstlane(wid * 8);
        float acc[8];
        const float bv = b_enc[lane];
        #pragma unroll
        for (int n = 0; n < 8; ++n) acc[n] = bv;
        #pragma unroll 2
        for (int k = 0; k < ENC; ++k) {
            const float wv = W_enc[k*HID + lane];       // per-lane, L1-resident
            #pragma unroll
            for (int n = 0; n < 8; ++n) {
                int ii = i0 + n; if (ii > NN-1) ii = NN-1;   // clamp (tail task)
                acc[n] = fmaf(enc[ii*ENC + k], wv, acc[n]);  // uniform -> s_load
            }
        }
        #pragma unroll
        for (int n = 0; n < 8; ++n)
            if (i0 + n < NN) sX[(i0+n)*RS + lane] = acc[n];
    }
    // ======== Phase A2 (all waves): d1 = ea@p1 -> sD ; G = relu(ea)@We -> global ====
    {
        float p1r[EDIM], Wer[EDIM*EDIM];
        #pragma unroll
        for (int k = 0; k < EDIM; ++k) p1r[k] = p1[k];
        #pragma unroll
        for (int u = 0; u < EDIM*EDIM; ++u) Wer[u] = We[u];
        for (int t = tid; t < EE; t += 1024) {
            float r[EDIM];
            #pragma unroll
            for (int m = 0; m < EDIM; ++m) r[m] = ea[t*EDIM + m];
            float a0 = 0.f;
            #pragma unroll
            for (int k = 0; k < EDIM; ++k) a0 = fmaf(r[k], p1r[k], a0);
            sD[t] = a0;
            #pragma unroll
            for (int k = 0; k < EDIM; ++k) {
                float g = 0.f;
                #pragma unroll
                for (int m = 0; m < EDIM; ++m) g = fmaf(fmaxf(r[m], 0.f), Wer[m*EDIM + k], g);
                G[t*EDIM + k] = g;
            }
        }
    }
    __syncthreads();

    // ======== Phase A3: Y1 = X@W1 (no bias; b1 added in B) ========
    if (wid < 15) {
        const int i0 = __builtin_amdgcn_readfirstlane(wid * 8);
        int ib[8];
        #pragma unroll
        for (int n = 0; n < 8; ++n) { int ii = i0 + n; ib[n] = (ii > NN-1 ? NN-1 : ii)*RS; }
        float acc[8];
        #pragma unroll
        for (int n = 0; n < 8; ++n) acc[n] = 0.f;
        for (int k = 0; k < HID; k += 4) {
            float4 xv[8];
            #pragma unroll
            for (int n = 0; n < 8; ++n) xv[n] = *(const float4*)&sX[ib[n] + k];  // uniform b128 bcast
            #pragma unroll
            for (int q = 0; q < 4; ++q) {
                const float wv = W1[(k+q)*HID + lane];
                #pragma unroll
                for (int n = 0; n < 8; ++n) {
                    const float x = (q==0) ? xv[n].x : (q==1) ? xv[n].y : (q==2) ? xv[n].z : xv[n].w;
                    acc[n] = fmaf(x, wv, acc[n]);
                }
            }
        }
        #pragma unroll
        for (int n = 0; n < 8; ++n)
            if (i0 + n < NN) sY1[(i0+n)*RS + lane] = acc[n];
    }
    __syncthreads();

    // ======== Phase B1: x2 = relu(D1@Y1 + b1); dv partials (4 waves, lane=node) ====
    if (wid < 4) {
        const int ihalf = __builtin_amdgcn_readfirstlane(wid >> 1);
        const int hh    = __builtin_amdgcn_readfirstlane((wid & 1) * 32);
        const int i  = ihalf*64 + lane;
        const bool vi = (i < NN);
        const int ic = vi ? i : 0;
        float acc[32];
        #pragma unroll
        for (int q = 0; q < 32; ++q) acc[q] = b1[hh + q];
        for (int j = 0; j < NN; ++j) {
            const int jj = (j == ic) ? (ic ^ 1) : j;
            const float dval = (j == ic) ? 0.f : sD[eid_ij(ic, jj)];
            const float4* yr = (const float4*)&sY1[j*RS + hh];
            #pragma unroll
            for (int q4 = 0; q4 < 8; ++q4) {
                const float4 y = yr[q4];
                acc[4*q4+0] = fmaf(dval, y.x, acc[4*q4+0]);
                acc[4*q4+1] = fmaf(dval, y.y, acc[4*q4+1]);
                acc[4*q4+2] = fmaf(dval, y.z, acc[4*q4+2]);
                acc[4*q4+3] = fmaf(dval, y.w, acc[4*q4+3]);
            }
        }
        float dvp = 0.f;
        #pragma unroll
        for (int q4 = 0; q4 < 8; ++q4) {
            float4 v;
            v.x = fmaxf(acc[4*q4+0], 0.f);
            v.y = fmaxf(acc[4*q4+1], 0.f);
            v.z = fmaxf(acc[4*q4+2], 0.f);
            v.w = fmaxf(acc[4*q4+3], 0.f);
            dvp = fmaf(v.x, pe[hh+4*q4+0], dvp);
            dvp = fmaf(v.y, pe[hh+4*q4+1], dvp);
            dvp = fmaf(v.z, pe[hh+4*q4+2], dvp);
            dvp = fmaf(v.w, pe[hh+4*q4+3], dvp);
            if (vi) *(float4*)&sX[i*RS + hh + 4*q4] = v;    // x2 overwrites X (dead)
        }
        sDvP[wid*64 + lane] = vi ? dvp : 0.f;
    }
    __syncthreads();

    // ======== Phase B2: Y2 = x2@W2 (waves 0..14) ; dv combine (wave 15) ========
    if (wid < 15) {
        const int i0 = __builtin_amdgcn_readfirstlane(wid * 8);
        int ib[8];
        #pragma unroll
        for (int n = 0; n < 8; ++n) { int ii = i0 + n; ib[n] = (ii > NN-1 ? NN-1 : ii)*RS; }
        float acc[8];
        #pragma unroll
        for (int n = 0; n < 8; ++n) acc[n] = 0.f;
        for (int k = 0; k < HID; k += 4) {
            float4 xv[8];
            #pragma unroll
            for (int n = 0; n < 8; ++n) xv[n] = *(const float4*)&sX[ib[n] + k];
            #pragma unroll
            for (int q = 0; q < 4; ++q) {
                const float wv = W2[(k+q)*HID + lane];
                #pragma unroll
                for (int n = 0; n < 8; ++n) {
                    const float x = (q==0) ? xv[n].x : (q==1) ? xv[n].y : (q==2) ? xv[n].z : xv[n].w;
                    acc[n] = fmaf(x, wv, acc[n]);
                }
            }
        }
        #pragma unroll
        for (int n = 0; n < 8; ++n)
            if (i0 + n < NN) sY2[(i0+n)*RS + lane] = acc[n];
    } else {
        // dv[i] = partial(h<32) + partial(h>=32)
        sDv[lane] = sDvP[lane] + sDvP[64 + lane];
        if (lane < NN - 64) sDv[64 + lane] = sDvP[128 + lane] + sDvP[192 + lane];
    }
    __syncthreads();

    // ======== Phase C: S[i,k] = sum_{j!=i} G[eid(i,j),k] / (max(dv_i,dv_j,0)+eps) ====
    for (int it = 0; it < (NN*EDIM + 15)/16; ++it) {
        const int wg = __builtin_amdgcn_readfirstlane(wid + it*16);
        if (wg < NN*EDIM) {
            const int i = wg / EDIM, k = wg - i*EDIM;
            const float di = sDv[i];
            float a = 0.f;
            #pragma unroll
            for (int rep = 0; rep < 2; ++rep) {
                const int j = lane + rep*64;
                if (j < NN && j != i) {
                    const float cm = fmaxf(fmaxf(di, sDv[j]), 0.f) + EPSF;
                    a += G[eid_ij(i, j)*EDIM + k] / cm;
                }
            }
            #pragma unroll
            for (int off = 32; off > 0; off >>= 1) a += __shfl_down(a, off, 64);
            if (lane == 0) sS[wg] = a;
        }
    }
    if (tid < HID) sP[tid] = 0.f;
    __syncthreads();

    // ======== Phase D: d2[e] = relu(edge_conv row) . p2  -> sD (d1 dead) ========
    {
        float ber[EDIM], p2r[EDIM];
        #pragma unroll
        for (int k = 0; k < EDIM; ++k) { ber[k] = be[k]; p2r[k] = p2[k]; }
        for (int t = tid; t < EE; t += 1024) {
            const int a = eidx[t], b = eidx[EE + t];
            const float da = sDv[a], db = sDv[b];
            const float rc = 1.f / (fmaxf(fmaxf(da, db), 0.f) + EPSF);
            float acc = 0.f;
            #pragma unroll
            for (int kk = 0; kk < EDIM; ++kk) {
                const float gp = G[t*EDIM + kk] * rc;
                const float v = fmaf(da, sS[a*EDIM + kk] - gp,
                               fmaf(db, sS[b*EDIM + kk] - gp, ber[kk]));
                acc = fmaf(fmaxf(v, 0.f), p2r[kk], acc);
            }
            sD[t] = acc;
        }
    }
    __syncthreads();

    // ======== Phase E: x3 = D2@Y2 + b2 ; pool into sP (4 waves, lane=node) ========
    if (wid < 4) {
        const int ihalf = __builtin_amdgcn_readfirstlane(wid >> 1);
        const int hh    = __builtin_amdgcn_readfirstlane((wid & 1) * 32);
        const int i  = ihalf*64 + lane;
        const bool vi = (i < NN);
        const int ic = vi ? i : 0;
        float acc[32];
        #pragma unroll
        for (int q = 0; q < 32; ++q) acc[q] = b2[hh + q];
        for (int j = 0; j < NN; ++j) {
            const int jj = (j == ic) ? (ic ^ 1) : j;
            const float dval = (j == ic) ? 0.f : sD[eid_ij(ic, jj)];
            const float4* yr = (const float4*)&sY2[j*RS + hh];
            #pragma unroll
            for (int q4 = 0; q4 < 8; ++q4) {
                const float4 y = yr[q4];
                acc[4*q4+0] = fmaf(dval, y.x, acc[4*q4+0]);
                acc[4*q4+1] = fmaf(dval, y.y, acc[4*q4+1]);
                acc[4*q4+2] = fmaf(dval, y.z, acc[4*q4+2]);
                acc[4*q4+3] = fmaf(dval, y.w, acc[4*q4+3]);
            }
        }
        #pragma unroll
        for (int q = 0; q < 32; ++q) {
            float r = vi ? acc[q] : 0.f;
            #pragma unroll
            for (int off = 32; off > 0; off >>= 1) r += __shfl_down(r, off, 64);
            if (lane == 0) atomicAdd(&sP[hh + q], r);
        }
    }
    __syncthreads();

    // ======== Phase F: out = (P/N) @ Wl + bl ========
    if (wid == 0) {
        const float val = sP[lane] * (1.0f / NN);
        float res[OUTD];
        #pragma unroll
        for (int o = 0; o < OUTD; ++o) {
            float r = val * Wl[lane*OUTD + o];
            #pragma unroll
            for (int off = 32; off > 0; off >>= 1) r += __shfl_xor(r, off, 64);
            res[o] = r;
        }
        if (lane < OUTD) out[lane] = res[lane] + bl[lane];
    }
}

extern "C" void kernel_launch(void* const* d_in, const int* in_sizes, int n_in,
                              void* d_out, int out_size, void* d_ws, size_t ws_size,
                              hipStream_t stream)
{
    const float* enc   = (const float*)d_in[0];
    const float* ea    = (const float*)d_in[1];
    const int*   eidx  = (const int*)  d_in[2];
    const float* W_enc = (const float*)d_in[3];
    const float* b_enc = (const float*)d_in[4];
    const float* W1    = (const float*)d_in[5];
    const float* b1    = (const float*)d_in[6];
    const float* p1    = (const float*)d_in[7];
    const float* We    = (const float*)d_in[8];
    const float* be    = (const float*)d_in[9];
    const float* pe    = (const float*)d_in[10];
    const float* W2    = (const float*)d_in[11];
    const float* b2    = (const float*)d_in[12];
    const float* p2    = (const float*)d_in[13];
    const float* Wl    = (const float*)d_in[14];
    const float* bl    = (const float*)d_in[15];
    float* G   = (float*)d_ws;          // [EE*EDIM] only global scratch
    float* out = (float*)d_out;

    fused1<<<1, 1024, 0, stream>>>(enc, ea, eidx, W_enc, b_enc, W1, b1, p1,
                                   We, be, pe, W2, b2, p2, Wl, bl, G, out);
}

// Round 3
// 204.722 us; speedup vs baseline: 1.8966x; 1.8966x over previous
//
#include <hip/hip_runtime.h>

// Net_3152505995417: tiny GNN forward (N=116, E=6670, HID=64, EDIM=5).
// R5: 3 plain dispatches (was 6 in the 126us best; coop-sync [R1: 14us/barrier]
// and single-block [R2: 1-CU latency-bound] both regressed).
//  K1 = phase A (X, Y1 node-local; d1, G edge-local)        [R0-verified code]
//  K2 = phase B (x2, dv, Y2; needs full Y1+d1)              [R0-verified code]
//  K3 = phases C+D+E+F fused:
//    C: S[i,k] = sum_{e=(a,b)} Gp[e,k] scattered to a,b -- rebuilt redundantly
//       per block in LDS via chunked edge sweep + LDS atomicAdd (~4-way cont.).
//    D: d2 only for the block's own 4 rows (460 edges), edge-local given S.
//    E: x3 rows + partial pool -> global atomicAdd P.
//    F: last-block-finishes (threadfence + agent-scope counter) computes head.
// Only fp-order change vs verified math: S accumulation order (~1e-6).

#define NN   116
#define EE   6670
#define HID  64
#define EDIM 5
#define OUTD 4
#define ENC  122
#define EPSF 1e-10f
#define NH   (NN*HID)   // 7424
#define CH   27         // ceil(EE/256) edge-chunk per thread in K3 scatter

__device__ __forceinline__ int eid_ij(int i, int j) {
    int a = i < j ? i : j;
    int b = i < j ? j : i;
    return a*NN - ((a*(a+1)) >> 1) + (b - a - 1);   // triu k=1 row-major
}

// K1: node blocks (0..28): X row = enc@W_enc+b_enc (LDS), Y1 row = Xrow@W1.
//     edge blocks (29..): d1 = ea@p1 ; G = relu(ea)@We.
__global__ __launch_bounds__(256) void kA(
    const float* __restrict__ enc, const float* __restrict__ ea,
    const float* __restrict__ W_enc, const float* __restrict__ b_enc,
    const float* __restrict__ p1, const float* __restrict__ We,
    const float* __restrict__ W1,
    float* __restrict__ Y1, float* __restrict__ d1, float* __restrict__ G)
{
    const int tid = threadIdx.x;
    if (blockIdx.x < 29) {
        __shared__ __align__(16) float sWe[ENC*HID];   // 31232 B
        __shared__ __align__(16) float sW1[HID*HID];   // 16384 B
        __shared__ __align__(16) float sEnc[4*ENC];    //  1952 B
        __shared__ float sX[4*HID];
        {
            const float4* g4 = (const float4*)W_enc; float4* s4 = (float4*)sWe;
            for (int u = tid; u < ENC*HID/4; u += 256) s4[u] = g4[u];
        }
        {
            const float4* g4 = (const float4*)W1; float4* s4 = (float4*)sW1;
            for (int u = tid; u < HID*HID/4; u += 256) s4[u] = g4[u];
        }
        {
            const float4* g4 = (const float4*)(enc + blockIdx.x*4*ENC); // 1952B-aligned
            float4* s4 = (float4*)sEnc;
            for (int u = tid; u < 4*ENC/4; u += 256) s4[u] = g4[u];
        }
        __syncthreads();
        const int w = tid >> 6, h = tid & 63;
        const int i = blockIdx.x*4 + w;
        float acc = b_enc[h];
        const float* er = sEnc + w*ENC;
        #pragma unroll 4
        for (int k = 0; k < ENC; ++k) acc = fmaf(er[k], sWe[k*HID + h], acc);
        sX[w*HID + h] = acc;
        __syncthreads();
        float a2 = 0.f;
        const float* xr = sX + w*HID;
        #pragma unroll 8
        for (int k = 0; k < HID; ++k) a2 = fmaf(xr[k], sW1[k*HID + h], a2);
        Y1[i*HID + h] = a2;
    } else {
        int u = (blockIdx.x - 29)*256 + tid;
        if (u < EE) {
            const float* r = ea + u*EDIM;
            float a0 = 0.f;
            #pragma unroll
            for (int k = 0; k < EDIM; ++k) a0 = fmaf(r[k], p1[k], a0);
            d1[u] = a0;
        } else if (u < EE + EE*EDIM) {
            int idx = u - EE;
            int e = idx / EDIM, k = idx - e*EDIM;
            const float* r = ea + e*EDIM;
            float a0 = 0.f;
            #pragma unroll
            for (int m = 0; m < EDIM; ++m) a0 = fmaf(fmaxf(r[m], 0.f), We[m*EDIM + k], a0);
            G[idx] = a0;
        }
    }
}

// K2: x2 row = relu(D1@Y1 + b1); dv[i] = x2row.pe; Y2 row = x2row @ W2.
//     Block 0 also zeroes P and the completion counter for K3.
__global__ __launch_bounds__(256) void kB(
    const float* __restrict__ d1, const float* __restrict__ Y1,
    const float* __restrict__ b1, const float* __restrict__ pe,
    const float* __restrict__ W2,
    float* __restrict__ dv, float* __restrict__ Y2,
    float* __restrict__ P, int* __restrict__ cnt)
{
    __shared__ __align__(16) float sY[NH];   // 29696 B
    __shared__ __align__(16) float sD[EE];   // 26680 B
    __shared__ float sX2[4*HID];
    const int tid = threadIdx.x;
    if (blockIdx.x == 0) {
        if (tid < HID) P[tid] = 0.f;
        if (tid == 0) *cnt = 0;
    }
    {
        const float4* g4 = (const float4*)Y1; float4* s4 = (float4*)sY;
        for (int u = tid; u < NH/4; u += 256) s4[u] = g4[u];
        const float2* g2 = (const float2*)d1; float2* s2 = (float2*)sD;
        for (int u = tid; u < EE/2; u += 256) s2[u] = g2[u];
    }
    __syncthreads();
    const int w = tid >> 6, h = tid & 63;
    const int i = blockIdx.x*4 + w;
    float acc = b1[h];
    #pragma unroll 4
    for (int j = 0; j < NN; ++j) {
        int jj = (j == i) ? (j ^ 1) : j;
        float wgt = (j == i) ? 0.f : sD[eid_ij(i, jj)];
        acc = fmaf(wgt, sY[jj*HID + h], acc);
    }
    float v = fmaxf(acc, 0.f);
    float r = v * pe[h];
    #pragma unroll
    for (int off = 32; off > 0; off >>= 1) r += __shfl_down(r, off, 64);
    if (h == 0) dv[i] = r;
    sX2[w*HID + h] = v;
    __syncthreads();
    float a2 = 0.f;
    const float* xr = sX2 + w*HID;
    #pragma unroll 8
    for (int k = 0; k < HID; ++k) a2 = fmaf(xr[k], W2[k*HID + h], a2);
    Y2[i*HID + h] = a2;
}

// K3: per block (29 blocks, 4 output rows each):
//   stage Y2 + dv; rebuild full S in LDS by edge scatter (Gp = G*rc);
//   d2 for own 460 edges; x3 rows; pool -> atomicAdd P; last block does head.
__global__ __launch_bounds__(256) void kCDEF(
    const int* __restrict__ eidx, const float* __restrict__ G,
    const float* __restrict__ dvg, const float* __restrict__ Y2,
    const float* __restrict__ be, const float* __restrict__ p2,
    const float* __restrict__ b2, const float* __restrict__ Wl,
    const float* __restrict__ bl,
    float* __restrict__ P, int* __restrict__ cnt, float* __restrict__ out)
{
    __shared__ __align__(16) float sY[NH];     // 29696 B
    __shared__ float sS[NN*EDIM];              // 580
    __shared__ float sDv[NN];
    __shared__ float sD2[4*NN];
    __shared__ float sR[4*HID];
    __shared__ int sLast;
    const int tid = threadIdx.x;
    const int wid = tid >> 6, lane = tid & 63;

    // ---- stage ----
    {
        const float4* g4 = (const float4*)Y2; float4* s4 = (float4*)sY;
        for (int u = tid; u < NH/4; u += 256) s4[u] = g4[u];
    }
    if (tid < NN) sDv[tid] = dvg[tid];
    for (int u = tid; u < NN*EDIM; u += 256) sS[u] = 0.f;
    __syncthreads();

    // ---- C: S[i,k] = sum over incident edges of Gp[e,k] (chunked scatter) ----
    {
        const int t0 = tid * CH;
        const int t1 = (t0 + CH < EE) ? t0 + CH : EE;
        for (int t = t0; t < t1; ++t) {
            const int a = eidx[t], b = eidx[EE + t];
            const float rc = 1.f / (fmaxf(fmaxf(sDv[a], sDv[b]), 0.f) + EPSF);
            #pragma unroll
            for (int k = 0; k < EDIM; ++k) {
                const float gp = G[t*EDIM + k] * rc;
                atomicAdd(&sS[a*EDIM + k], gp);
                atomicAdd(&sS[b*EDIM + k], gp);
            }
        }
    }
    __syncthreads();

    // ---- D: d2 row for the block's 4 nodes (edge-local given S) ----
    {
        const int i = blockIdx.x*4 + wid;
        float ber[EDIM], p2r[EDIM];
        #pragma unroll
        for (int k = 0; k < EDIM; ++k) { ber[k] = be[k]; p2r[k] = p2[k]; }
        #pragma unroll
        for (int rep = 0; rep < 2; ++rep) {
            const int j = lane + rep*64;
            if (j < NN) {
                float val = 0.f;
                if (j != i) {
                    const int a = i < j ? i : j, b = i < j ? j : i;
                    const int e = a*NN - ((a*(a+1)) >> 1) + (b - a - 1);
                    const float da = sDv[a], db = sDv[b];
                    const float rc = 1.f / (fmaxf(fmaxf(da, db), 0.f) + EPSF);
                    #pragma unroll
                    for (int k = 0; k < EDIM; ++k) {
                        const float gp = G[e*EDIM + k] * rc;
                        const float v = fmaf(da, sS[a*EDIM + k] - gp,
                                       fmaf(db, sS[b*EDIM + k] - gp, ber[k]));
                        val = fmaf(fmaxf(v, 0.f), p2r[k], val);
                    }
                }
                sD2[wid*NN + j] = val;
            }
        }
    }
    __syncthreads();

    // ---- E: x3 row = D2@Y2 + b2 (diag weight already 0), partial pool ----
    {
        float acc = b2[lane];
        const float* d2r = sD2 + wid*NN;
        #pragma unroll 4
        for (int j = 0; j < NN; ++j)
            acc = fmaf(d2r[j], sY[j*HID + lane], acc);
        sR[wid*HID + lane] = acc;
    }
    __syncthreads();
    if (wid == 0) {
        float s4 = sR[lane] + sR[HID + lane] + sR[2*HID + lane] + sR[3*HID + lane];
        atomicAdd(&P[lane], s4);
    }
    __syncthreads();

    // ---- F: last block computes out = (P/N)@Wl + bl ----
    if (tid == 0) {
        __threadfence();
        int old = __hip_atomic_fetch_add(cnt, 1, __ATOMIC_ACQ_REL, __HIP_MEMORY_SCOPE_AGENT);
        sLast = (old == 28) ? 1 : 0;
    }
    __syncthreads();
    if (sLast && wid == 0) {
        const float pv = __hip_atomic_load(&P[lane], __ATOMIC_ACQUIRE, __HIP_MEMORY_SCOPE_AGENT);
        const float val = pv * (1.0f / NN);
        float res[OUTD];
        #pragma unroll
        for (int o = 0; o < OUTD; ++o) {
            float r = val * Wl[lane*OUTD + o];
            #pragma unroll
            for (int off = 32; off > 0; off >>= 1) r += __shfl_xor(r, off, 64);
            res[o] = r;
        }
        if (lane < OUTD) out[lane] = res[lane] + bl[lane];
    }
}

extern "C" void kernel_launch(void* const* d_in, const int* in_sizes, int n_in,
                              void* d_out, int out_size, void* d_ws, size_t ws_size,
                              hipStream_t stream)
{
    const float* enc   = (const float*)d_in[0];
    const float* ea    = (const float*)d_in[1];
    const int*   eidx  = (const int*)  d_in[2];
    const float* W_enc = (const float*)d_in[3];
    const float* b_enc = (const float*)d_in[4];
    const float* W1    = (const float*)d_in[5];
    const float* b1    = (const float*)d_in[6];
    const float* p1    = (const float*)d_in[7];
    const float* We    = (const float*)d_in[8];
    const float* be    = (const float*)d_in[9];
    const float* pe    = (const float*)d_in[10];
    const float* W2    = (const float*)d_in[11];
    const float* b2    = (const float*)d_in[12];
    const float* p2    = (const float*)d_in[13];
    const float* Wl    = (const float*)d_in[14];
    const float* bl    = (const float*)d_in[15];
    float* ws = (float*)d_ws;

    // Workspace (floats):
    float* Y1 = ws;                 // [NH]
    float* Y2 = ws + NH;            // [NH]
    float* d1 = ws + 2*NH;          // [EE]   (even offset: float2 staging ok)
    float* G  = d1 + EE;            // [EE*EDIM]
    float* dv = G + EE*EDIM;        // [NN]
    float* P  = dv + NN;            // [HID]
    int*  cnt = (int*)(P + HID);    // [1]
    float* out = (float*)d_out;

    kA<<<29 + (EE + EE*EDIM + 255)/256, 256, 0, stream>>>(enc, ea, W_enc, b_enc, p1, We, W1, Y1, d1, G);
    kB<<<29, 256, 0, stream>>>(d1, Y1, b1, pe, W2, dv, Y2, P, cnt);
    kCDEF<<<29, 256, 0, stream>>>(eidx, G, dv, Y2, be, p2, b2, Wl, bl, P, cnt, out);
}